// Round 8
// baseline (215.277 us; speedup 1.0000x reference)
//
#include <hip/hip_runtime.h>
#include <hip/hip_bf16.h>
#include <cstdint>
#include <cstddef>

typedef _Float16 half8 __attribute__((ext_vector_type(8)));
typedef float floatx16 __attribute__((ext_vector_type(16)));

#define DGRID 128
#define D3 (DGRID * DGRID * DGRID)
#define WSZ (2 * 27 * 4096)  // Whf halves

struct __attribute__((aligned(4))) I3 { int a, b, c; };  // 12B z-triple

// ---------------- prep (R7-frozen): weights->fragment order, scatter lookup,
// feats->fp16, zero rows. lookup NOT cleared: harness poisons ws to 0xAA;
// validity test (unsigned)v < M rejects poison and -1 alike (R7-proven).
// Whf layout (round-2 verified): for layer L, offset k, frag f=ct*4+kk, lane l,
// j: Whf[((L*27+k)*8+f)*512+l*8+j] = (fp16) W_L[k][kk*16+(l>>5)*8+j][ct*32+(l&31)]
__global__ void prep(const int* __restrict__ coords, const float* __restrict__ feats,
                     const float* __restrict__ W1, const float* __restrict__ W2,
                     int* __restrict__ lookup, _Float16* __restrict__ Whf,
                     _Float16* __restrict__ h0, _Float16* __restrict__ h, int M) {
    int tid = blockIdx.x * 256 + threadIdx.x;
    if (tid < WSZ) {
        int idx = tid;
        int j = idx & 7;
        int l = (idx >> 3) & 63;
        int f = (idx >> 9) & 7;
        int kL = idx >> 12;  // 0..53
        int k = kL % 27, L = kL / 27;
        int kk = f & 3, ct = f >> 2;
        int c = kk * 16 + (l >> 5) * 8 + j;
        int n = ct * 32 + (l & 31);
        const float* W = L ? W2 : W1;
        Whf[idx] = (_Float16)W[k * 4096 + c * 64 + n];
        return;
    }
    tid -= WSZ;
    if (tid < M) {
        int x = coords[3 * tid], y = coords[3 * tid + 1], z = coords[3 * tid + 2];
        lookup[(x * DGRID + y) * DGRID + z] = tid;
        return;
    }
    tid -= M;
    if (tid < 64) {  // zero rows: row M of h0 and h
        h0[(size_t)M * 64 + tid] = (_Float16)0.f;
        h[(size_t)M * 64 + tid] = (_Float16)0.f;
        return;
    }
    tid -= 64;
    if (tid < M * 8) {  // feats -> fp16, 8 elements per thread
        const float4* src = (const float4*)feats + (size_t)tid * 2;
        float4 f0 = src[0], f1 = src[1];
        half8 v;
        v[0] = (_Float16)f0.x; v[1] = (_Float16)f0.y;
        v[2] = (_Float16)f0.z; v[3] = (_Float16)f0.w;
        v[4] = (_Float16)f1.x; v[5] = (_Float16)f1.y;
        v[6] = (_Float16)f1.z; v[7] = (_Float16)f1.w;
        ((half8*)h0)[tid] = v;
    }
}

// R16: merged A-gather (R13 addressing) inside the R15-proven barrier skeleton.
// Model (fits R9/R12/R13/R15): cost = SCATTERED 16B requests; coalesced loads
// are ~free (R15). A staged per-iter via global_load_lds with 8 consecutive
// lanes covering one contiguous 128B row (1-2 L2 txn/row vs 8 scattered);
// per-iter __syncthreads drains the stage (R15 pattern). G21 both-sides
// swizzle: source slot c8^r8, read slot ^(lrow&7) -> 4-way conflict (1.58x).
// B = R9 register ring (R15 proved its LDS staging ~neutral; saves 16KB LDS).
// Each wave stages & reads ONLY its own 64 abuf rows -> no cross-wave hazard.
// LDS 46.6KB -> 3 blocks/CU (6 waves); 782 blocks ~= 1 round.
template <bool FIRST, bool OUT_F16>
__global__ __launch_bounds__(128, 2) void spconv(const _Float16* __restrict__ x,
                                                 const _Float16* __restrict__ Whf,
                                                 const float* __restrict__ bias,
                                                 const int* __restrict__ coords,
                                                 const int* __restrict__ lookup,
                                                 int* __restrict__ nbr,
                                                 void* __restrict__ outp, int M) {
    __shared__ int nvs[27 * 128];            // [k][row-in-tile]
    __shared__ _Float16 abuf[2][128 * 64];   // A dbuf: 128 rows x 128B, swizzled
    const int tid = threadIdx.x;
    const int lane = tid & 63;
    const int wid = tid >> 6;      // 0/1
    const int lrow = lane & 31;
    const int lhalf = lane >> 5;
    const int r8 = lane >> 3;      // 0..7 staging row-in-group
    const int c8 = lane & 7;       // 0..7 staging 16B slot
    const int mw = blockIdx.x * 128;
    const int wrow = wid * 64;     // wave's row base within tile

    // ---- fill the LDS neighbor slice: one row per thread (128 rows) ----
    {
        const int row = mw + tid;
        if constexpr (FIRST) {
            if (row < M) {
                int X = coords[3 * row], Y = coords[3 * row + 1], Z = coords[3 * row + 2];
                int zlo = Z - 1;
                if (zlo < 0) zlo = 0;
                if (zlo > DGRID - 3) zlo = DGRID - 3;
                const int zi = Z - zlo;
#pragma unroll
                for (int dx = -1; dx <= 1; ++dx)
#pragma unroll
                    for (int dy = -1; dy <= 1; ++dy) {
                        int nx = X + dx, ny = Y + dy;
                        int v0 = -1, v1 = -1, v2 = -1;
                        if (((unsigned)nx < DGRID) && ((unsigned)ny < DGRID)) {
                            I3 t = *(const I3*)(lookup + ((nx * DGRID + ny) * DGRID + zlo));
                            v0 = t.a; v1 = t.b; v2 = t.c;
                        }
#pragma unroll
                        for (int dz = -1; dz <= 1; ++dz) {
                            int zc = Z + dz;
                            int i = zi + dz;
                            int val = (i == 0) ? v0 : (i == 1) ? v1 : v2;
                            int nidx = M;
                            if (((unsigned)zc < DGRID) && ((unsigned)val < (unsigned)M))
                                nidx = val;
                            int k = (dx + 1) * 9 + (dy + 1) * 3 + (dz + 1);
                            nvs[k * 128 + tid] = nidx;
                            nbr[(size_t)k * M + row] = nidx;  // table for conv2
                        }
                    }
            } else {
#pragma unroll
                for (int k = 0; k < 27; ++k) nvs[k * 128 + tid] = M;  // zero row
            }
        } else {
            const int rc = row < M ? row : M - 1;
#pragma unroll
            for (int k = 0; k < 27; ++k) nvs[k * 128 + tid] = nbr[(size_t)k * M + rc];
        }
    }
    __syncthreads();  // nvs ready

    floatx16 acc[4];  // [rt*2+ct]
#pragma unroll
    for (int i = 0; i < 4; ++i)
#pragma unroll
        for (int j = 0; j < 16; ++j) acc[i][j] = 0.0f;

    const half8* wb = (const half8*)Whf + lane;

    auto loadB = [&](half8* dst, int k) {
#pragma unroll
        for (int f = 0; f < 8; ++f) dst[f] = wb[(k * 8 + f) * 64];
    };

    // stage the wave's 64 rows for offset k into abuf[buf]: 8 rows per instr,
    // 8 consecutive lanes cover one contiguous 128B row (slot fetched = c8^r8
    // so the linear LDS write lands source-swizzled; read XORs the same key).
    auto stageA = [&](int buf, int k) {
#pragma unroll
        for (int s = 0; s < 8; ++s) {
            int rr = wrow + s * 8 + r8;
            int nv = nvs[k * 128 + rr];
            const _Float16* src = x + (size_t)nv * 64 + (c8 ^ r8) * 8;
            __builtin_amdgcn_global_load_lds(
                (const __attribute__((address_space(1))) void*)src,
                (__attribute__((address_space(3))) void*)&abuf[buf][(wrow + s * 8) * 64],
                16, 0, 0);
        }
    };

    // read A fragment for row-group rt from abuf[buf] (swizzled ds_read_b128)
    auto readA = [&](half8* dst, int buf, int rt) {
        const _Float16* base = &abuf[buf][(wrow + rt * 32 + lrow) * 64];
        const int key = lrow & 7;
#pragma unroll
        for (int kk = 0; kk < 4; ++kk) {
            int slot = (lhalf + kk * 2) ^ key;
            dst[kk] = *(const half8*)(base + slot * 8);
        }
    };

    half8 Br[2][8];
    stageA(0, 0);
    loadB(Br[0], 0);
    __syncthreads();  // drains stage(0) (vmcnt0 before barrier)

#pragma unroll
    for (int i = 0; i < 27; ++i) {
        if (i + 1 < 27) {
            stageA((i + 1) & 1, i + 1);   // DMA first: start early
            loadB(Br[(i + 1) & 1], i + 1);
        }
        half8 a0[4], a1[4];
        readA(a0, i & 1, 0);
        readA(a1, i & 1, 1);
        __builtin_amdgcn_sched_barrier(0);
        __syncthreads();  // drains stage(i+1)+B (vmcnt) and readA (lgkm)
        half8* B = Br[i & 1];
#pragma unroll
        for (int kk = 0; kk < 4; ++kk)
#pragma unroll
            for (int ct = 0; ct < 2; ++ct) {
                acc[0 * 2 + ct] = __builtin_amdgcn_mfma_f32_32x32x16_f16(
                    a0[kk], B[ct * 4 + kk], acc[0 * 2 + ct], 0, 0, 0);
                acc[1 * 2 + ct] = __builtin_amdgcn_mfma_f32_32x32x16_f16(
                    a1[kk], B[ct * 4 + kk], acc[1 * 2 + ct], 0, 0, 0);
            }
    }

    // epilogue: bias + relu; C/D: col=lane&31, row=(reg&3)+8*(reg>>2)+4*lhalf
    const float bv0 = bias[lrow], bv1 = bias[32 + lrow];
#pragma unroll
    for (int rt = 0; rt < 2; ++rt)
#pragma unroll
        for (int ct = 0; ct < 2; ++ct) {
            const float bb = ct ? bv1 : bv0;
#pragma unroll
            for (int reg = 0; reg < 16; ++reg) {
                int row = (reg & 3) + 8 * (reg >> 2) + 4 * lhalf;
                int g = mw + wrow + rt * 32 + row;
                if (g < M) {
                    float v = acc[rt * 2 + ct][reg] + bb;
                    v = v > 0.f ? v : 0.f;
                    size_t off = (size_t)g * 64 + ct * 32 + lrow;
                    if constexpr (OUT_F16)
                        ((_Float16*)outp)[off] = (_Float16)v;
                    else
                        ((float*)outp)[off] = v;
                }
            }
        }
}

extern "C" void kernel_launch(void* const* d_in, const int* in_sizes, int n_in,
                              void* d_out, int out_size, void* d_ws, size_t ws_size,
                              hipStream_t stream) {
    const float* feats = (const float*)d_in[0];
    const float* W1 = (const float*)d_in[1];
    const float* b1 = (const float*)d_in[2];
    const float* W2 = (const float*)d_in[3];
    const float* b2 = (const float*)d_in[4];
    const int* coords = (const int*)d_in[5];
    const int M = in_sizes[0] / 64;

    // workspace (~45.2 MB; fits, confirmed R5-R9):
    int* lookup = (int*)d_ws;                           // D3 ints (uncleared)
    int* nbr = lookup + (size_t)D3;                     // 27*M ints
    _Float16* h = (_Float16*)(nbr + (size_t)27 * M);    // (M+1)*64 halves
    _Float16* h0 = h + (size_t)(M + 1) * 64;            // (M+1)*64 halves
    _Float16* Whf = h0 + (size_t)(M + 1) * 64;          // WSZ halves
    size_t need = (size_t)D3 * 4 + (size_t)27 * M * 4 +
                  2 * (size_t)(M + 1) * 64 * 2 + (size_t)WSZ * 2;
    if (ws_size < need) return;

    long long pt = (long long)WSZ + M + 64 + (long long)M * 8;
    prep<<<(int)((pt + 255) / 256), 256, 0, stream>>>(coords, feats, W1, W2, lookup, Whf,
                                                      h0, h, M);

    int cb = (M + 127) / 128;
    spconv<true, true><<<cb, 128, 0, stream>>>(h0, Whf, b1, coords, lookup, nbr,
                                               (void*)h, M);
    spconv<false, false><<<cb, 128, 0, stream>>>(h, Whf + (size_t)27 * 4096, b2, coords,
                                                 lookup, nbr, d_out, M);
}

// Round 9
// 205.520 us; speedup vs baseline: 1.0475x; 1.0475x over previous
//
#include <hip/hip_runtime.h>
#include <hip/hip_bf16.h>
#include <cstdint>
#include <cstddef>

typedef _Float16 half8 __attribute__((ext_vector_type(8)));
typedef float floatx16 __attribute__((ext_vector_type(16)));

#define DGRID 128
#define D3 (DGRID * DGRID * DGRID)
#define WSZ (2 * 27 * 4096)  // Whf halves

struct __attribute__((aligned(4))) I3 { int a, b, c; };  // 12B z-triple

// ---------------- prep (R7-frozen): weights->fragment order, scatter lookup,
// feats->fp16, zero rows. lookup NOT cleared: harness poisons ws to 0xAA;
// validity test (unsigned)v < M rejects poison and -1 alike (R7-proven).
// Whf layout (round-2 verified): for layer L, offset k, frag f=ct*4+kk, lane l,
// j: Whf[((L*27+k)*8+f)*512+l*8+j] = (fp16) W_L[k][kk*16+(l>>5)*8+j][ct*32+(l&31)]
__global__ void prep(const int* __restrict__ coords, const float* __restrict__ feats,
                     const float* __restrict__ W1, const float* __restrict__ W2,
                     int* __restrict__ lookup, _Float16* __restrict__ Whf,
                     _Float16* __restrict__ h0, _Float16* __restrict__ h, int M) {
    int tid = blockIdx.x * 256 + threadIdx.x;
    if (tid < WSZ) {
        int idx = tid;
        int j = idx & 7;
        int l = (idx >> 3) & 63;
        int f = (idx >> 9) & 7;
        int kL = idx >> 12;  // 0..53
        int k = kL % 27, L = kL / 27;
        int kk = f & 3, ct = f >> 2;
        int c = kk * 16 + (l >> 5) * 8 + j;
        int n = ct * 32 + (l & 31);
        const float* W = L ? W2 : W1;
        Whf[idx] = (_Float16)W[k * 4096 + c * 64 + n];
        return;
    }
    tid -= WSZ;
    if (tid < M) {
        int x = coords[3 * tid], y = coords[3 * tid + 1], z = coords[3 * tid + 2];
        lookup[(x * DGRID + y) * DGRID + z] = tid;
        return;
    }
    tid -= M;
    if (tid < 64) {  // zero rows: row M of h0 and h
        h0[(size_t)M * 64 + tid] = (_Float16)0.f;
        h[(size_t)M * 64 + tid] = (_Float16)0.f;
        return;
    }
    tid -= 64;
    if (tid < M * 8) {  // feats -> fp16, 8 elements per thread
        const float4* src = (const float4*)feats + (size_t)tid * 2;
        float4 f0 = src[0], f1 = src[1];
        half8 v;
        v[0] = (_Float16)f0.x; v[1] = (_Float16)f0.y;
        v[2] = (_Float16)f0.z; v[3] = (_Float16)f0.w;
        v[4] = (_Float16)f1.x; v[5] = (_Float16)f1.y;
        v[6] = (_Float16)f1.z; v[7] = (_Float16)f1.w;
        ((half8*)h0)[tid] = v;
    }
}

// R17: row-merged A-gather via REGISTER staging (not global_load_lds).
// Surviving model: per-CU scattered-line throughput (~0.35 lines/cyc/CU) is
// the wall; R9's A pattern = 32 lines/instr (2-lane merge), 256 lines/iter
// -> 50us floor. Fix: 8 consecutive lanes cover one contiguous 128B row
// (8 lines/instr, 64/iter), staged global->reg (2-deep ring) -> ds_write_b128
// (write-side XOR swizzle) -> LDS 3-ring -> swizzled ds_read_b128 -> MFMA.
// DMA path avoided (R13/R16 proved it slow for scattered rows); single-wave
// blocks keep the loop barrier-free; B = R9-proven register ring dist 1.
// Ring algebra: iter i: gload k=i+2 -> G[i&1]; swrite k=i+1 from G[(i+1)&1]
// -> abuf[(i+1)%3]; consume abuf[i%3] (written at iter i-1). DS ops are
// in-order per wave -> no extra fences; compiler inserts exact vmcnt/lgkm.
template <bool FIRST, bool OUT_F16>
__global__ __launch_bounds__(64, 2) void spconv(const _Float16* __restrict__ x,
                                                const _Float16* __restrict__ Whf,
                                                const float* __restrict__ bias,
                                                const int* __restrict__ coords,
                                                const int* __restrict__ lookup,
                                                int* __restrict__ nbr,
                                                void* __restrict__ outp, int M) {
    __shared__ int nvs[27 * 64];           // [k][row-in-tile]
    __shared__ _Float16 abuf[3][64 * 64];  // A ring: 64 rows x 128B, swizzled
    const int lane = threadIdx.x;
    const int lrow = lane & 31;
    const int lhalf = lane >> 5;
    const int srow = lane >> 3;  // staging: row-in-group 0..7
    const int schk = lane & 7;   // staging: 16B chunk 0..7
    const int mw = blockIdx.x * 64;

    // ---- fill the LDS neighbor slice for this tile ----
    {
        const int row = mw + lane;
        if constexpr (FIRST) {
            if (row < M) {
                int X = coords[3 * row], Y = coords[3 * row + 1], Z = coords[3 * row + 2];
                int zlo = Z - 1;
                if (zlo < 0) zlo = 0;
                if (zlo > DGRID - 3) zlo = DGRID - 3;
                const int zi = Z - zlo;
#pragma unroll
                for (int dx = -1; dx <= 1; ++dx)
#pragma unroll
                    for (int dy = -1; dy <= 1; ++dy) {
                        int nx = X + dx, ny = Y + dy;
                        int v0 = -1, v1 = -1, v2 = -1;
                        if (((unsigned)nx < DGRID) && ((unsigned)ny < DGRID)) {
                            I3 t = *(const I3*)(lookup + ((nx * DGRID + ny) * DGRID + zlo));
                            v0 = t.a; v1 = t.b; v2 = t.c;
                        }
#pragma unroll
                        for (int dz = -1; dz <= 1; ++dz) {
                            int zc = Z + dz;
                            int i = zi + dz;
                            int val = (i == 0) ? v0 : (i == 1) ? v1 : v2;
                            int nidx = M;
                            if (((unsigned)zc < DGRID) && ((unsigned)val < (unsigned)M))
                                nidx = val;
                            int k = (dx + 1) * 9 + (dy + 1) * 3 + (dz + 1);
                            nvs[k * 64 + lane] = nidx;
                            nbr[(size_t)k * M + row] = nidx;  // table for conv2
                        }
                    }
            } else {
#pragma unroll
                for (int k = 0; k < 27; ++k) nvs[k * 64 + lane] = M;  // zero row
            }
        } else {
            const int rc = row < M ? row : M - 1;
#pragma unroll
            for (int k = 0; k < 27; ++k) nvs[k * 64 + lane] = nbr[(size_t)k * M + rc];
        }
    }
    __syncthreads();

    floatx16 acc[4];  // [rt*2+ct]
#pragma unroll
    for (int i = 0; i < 4; ++i)
#pragma unroll
        for (int j = 0; j < 16; ++j) acc[i][j] = 0.0f;

    const half8* wb = (const half8*)Whf + lane;

    auto loadB = [&](half8* dst, int k) {
#pragma unroll
        for (int f = 0; f < 8; ++f) dst[f] = wb[(k * 8 + f) * 64];
    };

    // row-merged gather: instr s covers rows s*8..s*8+7; 8 consecutive lanes
    // fetch the row's 8 contiguous 16B chunks -> 8 lines/instr (vs 32 in R9).
    auto gload = [&](half8* g, int k) {
#pragma unroll
        for (int s = 0; s < 8; ++s) {
            int nv = nvs[k * 64 + s * 8 + srow];
            g[s] = *(const half8*)(x + (size_t)nv * 64 + schk * 8);
        }
    };
    // write-side XOR swizzle: row r chunk c lands at slot c^(r&7).
    auto swrite = [&](int buf, half8* g) {
        _Float16* bp = abuf[buf];
#pragma unroll
        for (int s = 0; s < 8; ++s)
            *(half8*)(bp + (size_t)(s * 8 + srow) * 64 + (schk ^ srow) * 8) = g[s];
    };
    // swizzled fragment read; chunk (lhalf+2kk) ^ (row&7) matches R9 layout.
    auto readA = [&](half8* dst, int buf, int rt) {
        const _Float16* base = abuf[buf] + (size_t)(rt * 32 + lrow) * 64;
        const int key = lrow & 7;
#pragma unroll
        for (int kk = 0; kk < 4; ++kk)
            dst[kk] = *(const half8*)(base + ((lhalf + kk * 2) ^ key) * 8);
    };

    half8 G[2][8], Br[2][8];
    gload(G[0], 0);
    gload(G[1], 1);
    loadB(Br[0], 0);
    swrite(0, G[0]);  // k=0 -> buf0 (compiler waits exact vmcnt)

#pragma unroll
    for (int i = 0; i < 27; ++i) {
        if (i + 2 < 27) gload(G[i & 1], i + 2);       // issue k=i+2 early
        if (i + 1 < 27) {
            swrite((i + 1) % 3, G[(i + 1) & 1]);      // land k=i+1 into LDS
            loadB(Br[(i + 1) & 1], i + 1);            // B distance 1
        }
        half8 a0[4], a1[4];
        readA(a0, i % 3, 0);
        readA(a1, i % 3, 1);
        __builtin_amdgcn_sched_barrier(0);
        half8* B = Br[i & 1];
#pragma unroll
        for (int kk = 0; kk < 4; ++kk)
#pragma unroll
            for (int ct = 0; ct < 2; ++ct) {
                acc[0 * 2 + ct] = __builtin_amdgcn_mfma_f32_32x32x16_f16(
                    a0[kk], B[ct * 4 + kk], acc[0 * 2 + ct], 0, 0, 0);
                acc[1 * 2 + ct] = __builtin_amdgcn_mfma_f32_32x32x16_f16(
                    a1[kk], B[ct * 4 + kk], acc[1 * 2 + ct], 0, 0, 0);
            }
    }

    // epilogue: bias + relu; C/D: col=lane&31, row=(reg&3)+8*(reg>>2)+4*lhalf
    const float bv0 = bias[lrow], bv1 = bias[32 + lrow];
#pragma unroll
    for (int rt = 0; rt < 2; ++rt)
#pragma unroll
        for (int ct = 0; ct < 2; ++ct) {
            const float bb = ct ? bv1 : bv0;
#pragma unroll
            for (int reg = 0; reg < 16; ++reg) {
                int row = (reg & 3) + 8 * (reg >> 2) + 4 * lhalf;
                int g = mw + rt * 32 + row;
                if (g < M) {
                    float v = acc[rt * 2 + ct][reg] + bb;
                    v = v > 0.f ? v : 0.f;
                    size_t off = (size_t)g * 64 + ct * 32 + lrow;
                    if constexpr (OUT_F16)
                        ((_Float16*)outp)[off] = (_Float16)v;
                    else
                        ((float*)outp)[off] = v;
                }
            }
        }
}

extern "C" void kernel_launch(void* const* d_in, const int* in_sizes, int n_in,
                              void* d_out, int out_size, void* d_ws, size_t ws_size,
                              hipStream_t stream) {
    const float* feats = (const float*)d_in[0];
    const float* W1 = (const float*)d_in[1];
    const float* b1 = (const float*)d_in[2];
    const float* W2 = (const float*)d_in[3];
    const float* b2 = (const float*)d_in[4];
    const int* coords = (const int*)d_in[5];
    const int M = in_sizes[0] / 64;

    // workspace (~45.2 MB; fits, confirmed R5-R9):
    int* lookup = (int*)d_ws;                           // D3 ints (uncleared)
    int* nbr = lookup + (size_t)D3;                     // 27*M ints
    _Float16* h = (_Float16*)(nbr + (size_t)27 * M);    // (M+1)*64 halves
    _Float16* h0 = h + (size_t)(M + 1) * 64;            // (M+1)*64 halves
    _Float16* Whf = h0 + (size_t)(M + 1) * 64;          // WSZ halves
    size_t need = (size_t)D3 * 4 + (size_t)27 * M * 4 +
                  2 * (size_t)(M + 1) * 64 * 2 + (size_t)WSZ * 2;
    if (ws_size < need) return;

    long long pt = (long long)WSZ + M + 64 + (long long)M * 8;
    prep<<<(int)((pt + 255) / 256), 256, 0, stream>>>(coords, feats, W1, W2, lookup, Whf,
                                                      h0, h, M);

    int cb = (M + 63) / 64;
    spconv<true, true><<<cb, 64, 0, stream>>>(h0, Whf, b1, coords, lookup, nbr,
                                              (void*)h, M);
    spconv<false, false><<<cb, 64, 0, stream>>>(h, Whf + (size_t)27 * 4096, b2, coords,
                                                lookup, nbr, d_out, M);
}